// Round 1
// 68.401 us; speedup vs baseline: 1.0157x; 1.0157x over previous
//
#include <hip/hip_runtime.h>

// Problem constants (from reference)
#define NUM_DAYS    4096
#define NUM_ATTR    512
#define MB_WIN      128
#define HID         500
#define NUM_BATCHES (NUM_DAYS - MB_WIN)        // 3968
#define NUM_Y       (NUM_BATCHES + MB_WIN - 1) // 4095 distinct day indices
#define OUT_ELEMS   (NUM_BATCHES * MB_WIN)     // 507904

// ---------------------------------------------------------------------------
// Kernel 1: fold the MLP:  v[a] = sum_h W1[a,h]*W2[h],  c = b1.W2 + b2
// One wave per output row; float4 lane-strided row reads.
// ---------------------------------------------------------------------------
__global__ __launch_bounds__(64) void k_fold_weights(
    const float* __restrict__ W1, const float* __restrict__ b1,
    const float* __restrict__ W2, const float* __restrict__ b2,
    float* __restrict__ v, float* __restrict__ c) {
    const int b    = blockIdx.x;
    const int lane = threadIdx.x;  // 0..63
    const float* src = (b < NUM_ATTR) ? (W1 + (size_t)b * HID) : b1;
    float acc = 0.f;
    // HID = 500 = 125 float4
    const float4* s4 = (const float4*)src;
    const float4* w4 = (const float4*)W2;
    #pragma unroll
    for (int j = lane; j < 125; j += 64) {
        float4 a = s4[j], w = w4[j];
        acc += a.x * w.x + a.y * w.y + a.z * w.z + a.w * w.w;
    }
    #pragma unroll
    for (int off = 32; off >= 1; off >>= 1) acc += __shfl_down(acc, off, 64);
    if (lane == 0) {
        if (b < NUM_ATTR) v[b] = acc;
        else              *c   = acc + b2[0];
    }
}

// ---------------------------------------------------------------------------
// Kernel 2: y[d] = x[d,:].v + c  for d in [0, NUM_Y).  One wave per day,
// 4 waves (4 days) per 256-thread block. Coalesced float4 reads of x;
// v/c are L1/L2-resident. No scatter — y is a dense 16 KB array in ws.
// ---------------------------------------------------------------------------
__global__ __launch_bounds__(256) void k_dot(
    const float* __restrict__ x, const float* __restrict__ v,
    const float* __restrict__ c, float* __restrict__ y) {
    const int wv   = threadIdx.x >> 6;   // wave in block, 0..3
    const int lane = threadIdx.x & 63;   // 0..63
    const int d    = (blockIdx.x << 2) | wv;
    if (d >= NUM_Y) return;

    const float4* xr = (const float4*)(x + (size_t)d * NUM_ATTR);
    const float4* vr = (const float4*)v;
    float4 a0 = xr[lane];
    float4 a1 = xr[lane + 64];
    float4 v0 = vr[lane];
    float4 v1 = vr[lane + 64];
    float acc = a0.x * v0.x + a0.y * v0.y + a0.z * v0.z + a0.w * v0.w
              + a1.x * v1.x + a1.y * v1.y + a1.z * v1.z + a1.w * v1.w;
    #pragma unroll
    for (int off = 32; off >= 1; off >>= 1) acc += __shfl_xor(acc, off, 64);
    if (lane == 0) y[d] = acc + *c;
}

// ---------------------------------------------------------------------------
// Kernel 3: replicate.  out row w (128 floats) == y[w .. w+127], contiguous.
// One float4 of out per thread: 4 scalar reads of the 16 KB L1-resident y,
// one fully-coalesced 16 B store.  126976 threads = 496 blocks x 256.
// ---------------------------------------------------------------------------
__global__ __launch_bounds__(256) void k_replicate(
    const float* __restrict__ y, float4* __restrict__ out4) {
    const int t = blockIdx.x * 256 + threadIdx.x;  // 0 .. 126975
    const int w = t >> 5;        // output row, 0..3967
    const int l = t & 31;        // float4 index within row
    const int base = w + (l << 2);
    float4 r;
    r.x = y[base + 0];
    r.y = y[base + 1];
    r.z = y[base + 2];
    r.w = y[base + 3];
    out4[t] = r;
}

extern "C" void kernel_launch(void* const* d_in, const int* in_sizes, int n_in,
                              void* d_out, int out_size, void* d_ws, size_t ws_size,
                              hipStream_t stream) {
    const float* x  = (const float*)d_in[0];  // [4096, 512]
    const float* W1 = (const float*)d_in[1];  // [512, 500]
    const float* b1 = (const float*)d_in[2];  // [500]
    const float* W2 = (const float*)d_in[3];  // [500, 1]
    const float* b2 = (const float*)d_in[4];  // [1]
    float* out = (float*)d_out;               // [507904]

    float* ws = (float*)d_ws;
    float* v  = ws;          // 512 floats
    float* c  = ws + 512;    // 1 float
    float* y  = ws + 576;    // 4095 floats (keep y 256B-aligned region)

    k_fold_weights<<<NUM_ATTR + 1, 64, 0, stream>>>(W1, b1, W2, b2, v, c);
    k_dot<<<(NUM_Y + 3) / 4, 256, 0, stream>>>(x, v, c, y);
    k_replicate<<<(OUT_ELEMS / 4) / 256, 256, 0, stream>>>(y, (float4*)out);
}